// Round 6
// baseline (531.664 us; speedup 1.0000x reference)
//
#include <hip/hip_runtime.h>
#include <math.h>

#define LAYERS 20
#define CS_FLOATS 480   // 20 layers * 12 qubits * {cos,sin}

// ---------------------------------------------------------------------------
// Pre-kernel: accurate cos/sin of theta/2 for layers 1..20 (weights[1:21]).
// ---------------------------------------------------------------------------
__global__ void cs_precompute(const float* __restrict__ qp, float* __restrict__ cs) {
    int i = threadIdx.x;
    if (i < 240) {
        float t = 0.5f * qp[12 + i];
        cs[2 * i]     = cosf(t);
        cs[2 * i + 1] = sinf(t);
    }
}

// ---------------------------------------------------------------------------
// R1-R5 lesson: the backend pins the VGPR budget at 64 (8 waves/EU target)
// regardless of launch_bounds / amdgpu_waves_per_eu, spilling any >64-float
// state to scratch (15-18MB HBM write-back, ~470us, three kernels identical).
// Fix BY CONSTRUCTION: 2 waves per row, 32 named-scalar amplitudes per lane
// (~55 VGPR demand < 64 budget -> nothing to spill).
//
// Index map: amplitude i = w<<11 | r<<6 | L. wave bit w = qubit 0 (never a
// CNOT target -> entangler never crosses waves). reg bits r4..r0 = qubits
// 1..5. lane bits L5..L0 = qubits 6..11 (unchanged from validated kernels).
//
// Entangler src map: src = i ^ (i>>1) ^ ((i>>2)&0x155).
//  - lane part: pl(L) = L ^ (L>>1) ^ ((L>>2)&5), ^48 iff dest reg bit0 set.
//  - reg part (5 bits), dest r -> src g(r): g4=r4, g3=r3^r4, g2=r2^r3^r4,
//    g1=r1^r2, g0=r0^r1^r2, PLUS ^16 iff w==1 (qubit-0 control feeding
//    qubit 1). Two static cycle decompositions under a wave-uniform branch:
//      w=0: (0)(1)(2 3)(4 7 5 6)(8 12 11 14)(9 13 10 15)
//           (16 28 23 25 17 29 22 24)(18 31 21 26 19 30 20 27)
//      w=1: (0 16 12 27 2 19 14 24)(1 17 13 26 3 18 15 25)
//           (4 23 9 29 6 20 11 30)(5 22 8 28 7 21 10 31)
// RY q0 = cross-wave pair (i, i^0x800): LDS exchange, 16 b64 writes/reads,
// padded stride 17 float2 (=34 dwords -> 2-way bank alias = free).
// ---------------------------------------------------------------------------
#define ALL32(F) F(0) F(1) F(2) F(3) F(4) F(5) F(6) F(7) F(8) F(9) F(10) F(11) \
  F(12) F(13) F(14) F(15) F(16) F(17) F(18) F(19) F(20) F(21) F(22) F(23) \
  F(24) F(25) F(26) F(27) F(28) F(29) F(30) F(31)

#define P16(F) F(0,16) F(1,17) F(2,18) F(3,19) F(4,20) F(5,21) F(6,22) F(7,23) \
  F(8,24) F(9,25) F(10,26) F(11,27) F(12,28) F(13,29) F(14,30) F(15,31)
#define P8(F) F(0,8) F(1,9) F(2,10) F(3,11) F(4,12) F(5,13) F(6,14) F(7,15) \
  F(16,24) F(17,25) F(18,26) F(19,27) F(20,28) F(21,29) F(22,30) F(23,31)
#define P4(F) F(0,4) F(1,5) F(2,6) F(3,7) F(8,12) F(9,13) F(10,14) F(11,15) \
  F(16,20) F(17,21) F(18,22) F(19,23) F(24,28) F(25,29) F(26,30) F(27,31)
#define P2(F) F(0,2) F(1,3) F(4,6) F(5,7) F(8,10) F(9,11) F(12,14) F(13,15) \
  F(16,18) F(17,19) F(20,22) F(21,23) F(24,26) F(25,27) F(28,30) F(29,31)
#define P1(F) F(0,1) F(2,3) F(4,5) F(6,7) F(8,9) F(10,11) F(12,13) F(14,15) \
  F(16,17) F(18,19) F(20,21) F(22,23) F(24,25) F(26,27) F(28,29) F(30,31)

// exchange pair lists (k, even idx, odd idx), split in 4 groups of 4
#define XL0(F) F(0,0,1)   F(1,2,3)   F(2,4,5)   F(3,6,7)
#define XL1(F) F(4,8,9)   F(5,10,11) F(6,12,13) F(7,14,15)
#define XL2(F) F(8,16,17) F(9,18,19) F(10,20,21) F(11,22,23)
#define XL3(F) F(12,24,25) F(13,26,27) F(14,28,29) F(15,30,31)

// ---------------------------------------------------------------------------
template <bool PRE>
__global__ __launch_bounds__(128)
void qsim(const float* __restrict__ feats,
          const float* __restrict__ qp,
          const float* __restrict__ cs,
          float* __restrict__ out)
{
    __shared__ float2 xch2[2 * 64 * 17];          // 17408 B
    float* xchf = (float*)xch2;

    const int tid  = threadIdx.x;
    const int lane = tid & 63;
    const int w    = tid >> 6;                    // wave bit = qubit 0
    const int row  = blockIdx.x;

    // entangler lane-permutation bpermute byte addresses
    const int sl0   = lane ^ (lane >> 1) ^ ((lane >> 2) & 5);
    const int addr0 = sl0 << 2;
    const int addr1 = (sl0 ^ 48) << 2;

    const int mybase = w * 1088 + lane * 17;      // float2 units
    const int pbase  = (1 - w) * 1088 + lane * 17;

#define DCL(r) float v##r;
    ALL32(DCL)
#undef DCL

    // ---- load + tanh + amplitude embedding ----
    const float* fr = feats + (size_t)row * 2048;
    if (w == 0) {                                 // amplitudes 0..2047 = features
        float fsum = 0.f;
#define LD(r) { float x_ = tanhf(fr[((r) << 6) + lane]) * 1.5707963267948966f; \
                v##r = x_; fsum += x_ * x_; }
        ALL32(LD)
#undef LD
#pragma unroll
        for (int m = 32; m >= 1; m >>= 1) fsum += __shfl_xor(fsum, m, 64);
        if (lane == 0) xchf[0] = fsum;
    }
    __syncthreads();
    const float inv = rsqrtf(xchf[0] + 512.0f);   // 2048 pads of 0.5^2
    __syncthreads();                              // protect xchf[0] before reuse
    if (w == 0) {
#define SC(r) v##r *= inv;
        ALL32(SC)
#undef SC
    } else {                                      // amplitudes 2048..4095 = 0.5
        const float padv = 0.5f * inv;
#define PD(r) v##r = padv;
        ALL32(PD)
#undef PD
    }

    // ---- 20 circuit layers ----
#pragma unroll 1
    for (int l = 0; l < LAYERS; ++l) {
        const float* csl = cs + l * 24;

        // ---- entangling layer ----
#define BPV(a, x) __int_as_float(__builtin_amdgcn_ds_bpermute( \
                      (((a) & 1) ? addr1 : addr0), __float_as_int(x)))
#define FIX(a) v##a = BPV(a, v##a);
#define C2(a,b) { float t_ = v##a; v##a = BPV(a, v##b); v##b = BPV(b, t_); }
#define C4(a,b,c,d) { float t_ = v##a; v##a = BPV(a, v##b); \
        v##b = BPV(b, v##c); v##c = BPV(c, v##d); v##d = BPV(d, t_); }
#define C8(a,b,c,d,e,f,g,h) { float t_ = v##a; v##a = BPV(a, v##b); \
        v##b = BPV(b, v##c); v##c = BPV(c, v##d); v##d = BPV(d, v##e); \
        v##e = BPV(e, v##f); v##f = BPV(f, v##g); v##g = BPV(g, v##h); \
        v##h = BPV(h, t_); }
        if (w == 0) {
            FIX(0) FIX(1)
            C2(2, 3)
            C4(4, 7, 5, 6)
            C4(8, 12, 11, 14)
            C4(9, 13, 10, 15)
            C8(16, 28, 23, 25, 17, 29, 22, 24)
            C8(18, 31, 21, 26, 19, 30, 20, 27)
        } else {
            C8(0, 16, 12, 27, 2, 19, 14, 24)
            C8(1, 17, 13, 26, 3, 18, 15, 25)
            C8(4, 23, 9, 29, 6, 20, 11, 30)
            C8(5, 22, 8, 28, 7, 21, 10, 31)
        }
#undef BPV
#undef FIX
#undef C2
#undef C4
#undef C8

        // ---- RY on reg-bit qubits 1..5 (masks 16,8,4,2,1) — pure VALU
#define RYP(a,b) { float a0_ = v##a, a1_ = v##b; \
        v##a = c_ * a0_ - s_ * a1_; v##b = s_ * a0_ + c_ * a1_; }
#define RYREG(J, LIST) { float c_, s_; \
        if constexpr (PRE) { c_ = csl[2*(J)]; s_ = csl[2*(J)+1]; } \
        else { float t_ = 0.5f * qp[12 + l*12 + (J)]; __sincosf(t_, &s_, &c_); } \
        LIST(RYP) }
        RYREG(1, P16)
        RYREG(2, P8)
        RYREG(3, P4)
        RYREG(4, P2)
        RYREG(5, P1)
#undef RYREG
#undef RYP

        // ---- RY on lane-bit qubits 6..11 (lane masks 32..1)
#define LRY(r) { float p_ = __shfl_xor(v##r, m, 64); v##r = c_ * v##r + ssel_ * p_; }
#pragma unroll
        for (int j = 0; j < 6; ++j) {
            float c_, s_;
            if constexpr (PRE) { c_ = csl[12 + 2*j]; s_ = csl[13 + 2*j]; }
            else { float t_ = 0.5f * qp[12 + l*12 + 6 + j]; __sincosf(t_, &s_, &c_); }
            const int m = 32 >> j;
            const float ssel_ = (lane & m) ? s_ : -s_;
            ALL32(LRY)
        }
#undef LRY

        // ---- RY on wave-bit qubit 0: LDS exchange of all 32 values
        {
            float c0_, s0_;
            if constexpr (PRE) { c0_ = csl[0]; s0_ = csl[1]; }
            else { float t_ = 0.5f * qp[12 + l*12]; __sincosf(t_, &s0_, &c0_); }
            const float ssel0_ = w ? s0_ : -s0_;
#define XW(k,a,b) xch2[mybase + (k)] = make_float2(v##a, v##b);
            XL0(XW) XL1(XW) XL2(XW) XL3(XW)
#undef XW
            __syncthreads();
#define XR(k,a,b) { float2 p_ = xch2[pbase + (k)]; \
        v##a = c0_ * v##a + ssel0_ * p_.x; \
        v##b = c0_ * v##b + ssel0_ * p_.y; }
            XL0(XR) __builtin_amdgcn_sched_barrier(0);
            XL1(XR) __builtin_amdgcn_sched_barrier(0);
            XL2(XR) __builtin_amdgcn_sched_barrier(0);
            XL3(XR)
#undef XR
            __syncthreads();   // reads done before next layer's writes
        }
    }

    // ---- PauliZ expectation values ----
    float T = 0.f;
#define SQT(r) v##r *= v##r; T += v##r;
    ALL32(SQT)
#undef SQT

    float part[12];
    part[0] = w ? -T : T;                        // qubit 0 sign = wave bit
#define ADDB(a,b) + v##b
    { float S;
      S = 0.f P16(ADDB); part[1] = T - 2.f * S;
      S = 0.f P8(ADDB);  part[2] = T - 2.f * S;
      S = 0.f P4(ADDB);  part[3] = T - 2.f * S;
      S = 0.f P2(ADDB);  part[4] = T - 2.f * S;
      S = 0.f P1(ADDB);  part[5] = T - 2.f * S; }
#undef ADDB
#pragma unroll
    for (int q = 6; q < 12; ++q) {
        const int m = 32 >> (q - 6);
        part[q] = (lane & m) ? -T : T;
    }
#pragma unroll
    for (int q = 0; q < 12; ++q) {
#pragma unroll
        for (int m2 = 32; m2 >= 1; m2 >>= 1) part[q] += __shfl_xor(part[q], m2, 64);
    }
    if (lane == 0) {
#pragma unroll
        for (int q = 0; q < 12; ++q) xchf[w * 12 + q] = part[q];
    }
    __syncthreads();
    if (tid < 12) out[row * 12 + tid] = xchf[tid] + xchf[12 + tid];
}

// ---------------------------------------------------------------------------
extern "C" void kernel_launch(void* const* d_in, const int* in_sizes, int n_in,
                              void* d_out, int out_size, void* d_ws, size_t ws_size,
                              hipStream_t stream) {
    (void)in_sizes; (void)n_in; (void)out_size;
    const float* feats = (const float*)d_in[0];   // (4096, 2048) fp32
    const float* qp    = (const float*)d_in[1];   // (252,) fp32
    float* out = (float*)d_out;                   // (4096, 12) fp32

    if (ws_size >= CS_FLOATS * sizeof(float)) {
        float* cs = (float*)d_ws;
        cs_precompute<<<1, 256, 0, stream>>>(qp, cs);
        qsim<true><<<4096, 128, 0, stream>>>(feats, qp, cs, out);
    } else {
        qsim<false><<<4096, 128, 0, stream>>>(feats, qp, nullptr, out);
    }
}

// Round 8
// 390.384 us; speedup vs baseline: 1.3619x; 1.3619x over previous
//
#include <hip/hip_runtime.h>
#include <math.h>

#define LAYERS 20
#define CS_FLOATS 480   // 20 layers * 12 qubits * {cos,sin}

// ---------------------------------------------------------------------------
// Pre-kernel: accurate cos/sin of theta/2 for layers 1..20 (weights[1:21]).
// ---------------------------------------------------------------------------
__global__ void cs_precompute(const float* __restrict__ qp, float* __restrict__ cs) {
    int i = threadIdx.x;
    if (i < 240) {
        float t = 0.5f * qp[12 + i];
        cs[2 * i]     = cosf(t);
        cs[2 * i + 1] = sinf(t);
    }
}

// ---------------------------------------------------------------------------
// R6 lesson: spill eliminated (WRITE 15.5MB -> 0.25MB) but time unchanged ->
// kernel is DS-pipe latency-bound (256 DS ops/layer/wave) at 42% occupancy.
// R7 changes: (1) lane-RY exchanges for masks 1,2,4,8 move to VALU DPP
// (quad_perm / row_shl+row_shr+cndmask): 256 -> 128 DS ops/layer.
// (2) q0 LDS exchange split in 2 phases of 8 float2: LDS 17408 -> 9216 B,
// occupancy cap 9 -> 16 blocks/CU (32 waves/CU).
//
// Index map: amplitude i = w<<11 | r<<6 | L. wave bit w = qubit 0 (never a
// CNOT target -> entangler never crosses waves). reg bits r4..r0 = qubits
// 1..5. lane bits L5..L0 = qubits 6..11.
// Entangler src map: src = i ^ (i>>1) ^ ((i>>2)&0x155).
//  - lane part: pl(L) = L ^ (L>>1) ^ ((L>>2)&5), ^48 iff dest reg bit0 set.
//  - reg part: two static cycle decompositions (w=0 / w=1) below.
// ---------------------------------------------------------------------------
#define ALL32(F) F(0) F(1) F(2) F(3) F(4) F(5) F(6) F(7) F(8) F(9) F(10) F(11) \
  F(12) F(13) F(14) F(15) F(16) F(17) F(18) F(19) F(20) F(21) F(22) F(23) \
  F(24) F(25) F(26) F(27) F(28) F(29) F(30) F(31)

#define P16(F) F(0,16) F(1,17) F(2,18) F(3,19) F(4,20) F(5,21) F(6,22) F(7,23) \
  F(8,24) F(9,25) F(10,26) F(11,27) F(12,28) F(13,29) F(14,30) F(15,31)
#define P8(F) F(0,8) F(1,9) F(2,10) F(3,11) F(4,12) F(5,13) F(6,14) F(7,15) \
  F(16,24) F(17,25) F(18,26) F(19,27) F(20,28) F(21,29) F(22,30) F(23,31)
#define P4(F) F(0,4) F(1,5) F(2,6) F(3,7) F(8,12) F(9,13) F(10,14) F(11,15) \
  F(16,20) F(17,21) F(18,22) F(19,23) F(24,28) F(25,29) F(26,30) F(27,31)
#define P2(F) F(0,2) F(1,3) F(4,6) F(5,7) F(8,10) F(9,11) F(12,14) F(13,15) \
  F(16,18) F(17,19) F(20,22) F(21,23) F(24,26) F(25,27) F(28,30) F(29,31)
#define P1(F) F(0,1) F(2,3) F(4,5) F(6,7) F(8,9) F(10,11) F(12,13) F(14,15) \
  F(16,17) F(18,19) F(20,21) F(22,23) F(24,25) F(26,27) F(28,29) F(30,31)

// q0-exchange pair lists (phase-local k, even reg, odd reg)
#define XA(F) F(0,0,1) F(1,2,3) F(2,4,5) F(3,6,7) F(4,8,9) F(5,10,11) F(6,12,13) F(7,14,15)
#define XB(F) F(0,16,17) F(1,18,19) F(2,20,21) F(3,22,23) F(4,24,25) F(5,26,27) F(6,28,29) F(7,30,31)

// DPP cross-lane fetch (VALU pipe, ~4cyc, replaces ds_swizzle/bpermute)
template <int CTRL>
__device__ __forceinline__ float dppf(float x) {
    return __int_as_float(__builtin_amdgcn_mov_dpp(
        __float_as_int(x), CTRL, 0xF, 0xF, true));
}

// ---------------------------------------------------------------------------
template <bool PRE>
__global__ __launch_bounds__(128)
void qsim(const float* __restrict__ feats,
          const float* __restrict__ qp,
          const float* __restrict__ cs,
          float* __restrict__ out)
{
    __shared__ float2 xch2[2 * 64 * 9];           // 9216 B
    float* xchf = (float*)xch2;

    const int tid  = threadIdx.x;
    const int lane = tid & 63;
    const int w    = tid >> 6;                    // wave bit = qubit 0
    const int row  = blockIdx.x;

    // entangler lane-permutation bpermute byte addresses
    const int sl0   = lane ^ (lane >> 1) ^ ((lane >> 2) & 5);
    const int addr0 = sl0 << 2;
    const int addr1 = (sl0 ^ 48) << 2;

    const int mybase = w * 576 + lane * 9;        // float2 units, pad stride 9
    const int pbase  = (1 - w) * 576 + lane * 9;

#define DCL(r) float v##r;
    ALL32(DCL)
#undef DCL

    // ---- load + tanh + amplitude embedding ----
    const float* fr = feats + (size_t)row * 2048;
    if (w == 0) {                                 // amplitudes 0..2047 = features
        float fsum = 0.f;
#define LD(r) { float x_ = tanhf(fr[((r) << 6) + lane]) * 1.5707963267948966f; \
                v##r = x_; fsum += x_ * x_; }
        ALL32(LD)
#undef LD
#pragma unroll
        for (int m = 32; m >= 1; m >>= 1) fsum += __shfl_xor(fsum, m, 64);
        if (lane == 0) xchf[0] = fsum;
    }
    __syncthreads();
    const float inv = rsqrtf(xchf[0] + 512.0f);   // 2048 pads of 0.5^2
    __syncthreads();                              // protect xchf[0] before reuse
    if (w == 0) {
#define SC(r) v##r *= inv;
        ALL32(SC)
#undef SC
    } else {                                      // amplitudes 2048..4095 = 0.5
        const float padv = 0.5f * inv;
#define PD(r) v##r = padv;
        ALL32(PD)
#undef PD
    }

    // ---- 20 circuit layers ----
#pragma unroll 1
    for (int l = 0; l < LAYERS; ++l) {
        const float* csl = cs + l * 24;

        // ---- entangling layer (32 ds_bpermute, in-place cycle rename) ----
#define BPV(a, x) __int_as_float(__builtin_amdgcn_ds_bpermute( \
                      (((a) & 1) ? addr1 : addr0), __float_as_int(x)))
#define FIX(a) v##a = BPV(a, v##a);
#define C2(a,b) { float t_ = v##a; v##a = BPV(a, v##b); v##b = BPV(b, t_); }
#define C4(a,b,c,d) { float t_ = v##a; v##a = BPV(a, v##b); \
        v##b = BPV(b, v##c); v##c = BPV(c, v##d); v##d = BPV(d, t_); }
#define C8(a,b,c,d,e,f,g,h) { float t_ = v##a; v##a = BPV(a, v##b); \
        v##b = BPV(b, v##c); v##c = BPV(c, v##d); v##d = BPV(d, v##e); \
        v##e = BPV(e, v##f); v##f = BPV(f, v##g); v##g = BPV(g, v##h); \
        v##h = BPV(h, t_); }
        if (w == 0) {
            FIX(0) FIX(1)
            C2(2, 3)
            C4(4, 7, 5, 6)
            C4(8, 12, 11, 14)
            C4(9, 13, 10, 15)
            C8(16, 28, 23, 25, 17, 29, 22, 24)
            C8(18, 31, 21, 26, 19, 30, 20, 27)
        } else {
            C8(0, 16, 12, 27, 2, 19, 14, 24)
            C8(1, 17, 13, 26, 3, 18, 15, 25)
            C8(4, 23, 9, 29, 6, 20, 11, 30)
            C8(5, 22, 8, 28, 7, 21, 10, 31)
        }
#undef BPV
#undef FIX
#undef C2
#undef C4
#undef C8

        // ---- RY on reg-bit qubits 1..5 (masks 16,8,4,2,1) — pure VALU
#define RYP(a,b) { float a0_ = v##a, a1_ = v##b; \
        v##a = c_ * a0_ - s_ * a1_; v##b = s_ * a0_ + c_ * a1_; }
#define RYREG(J, LIST) { float c_, s_; \
        if constexpr (PRE) { c_ = csl[2*(J)]; s_ = csl[2*(J)+1]; } \
        else { float t_ = 0.5f * qp[12 + l*12 + (J)]; __sincosf(t_, &s_, &c_); } \
        LIST(RYP) }
        RYREG(1, P16)
        RYREG(2, P8)
        RYREG(3, P4)
        RYREG(4, P2)
        RYREG(5, P1)
#undef RYREG
#undef RYP

        // ---- RY on lane-bit qubits 6..11 ----
        {
            float c_, s_, ssel_;
#define GETCS(jj) \
            if constexpr (PRE) { c_ = csl[12 + 2*(jj)]; s_ = csl[13 + 2*(jj)]; } \
            else { float t_ = 0.5f * qp[12 + l*12 + 6 + (jj)]; __sincosf(t_, &s_, &c_); }

            // qubit 6: mask 32 — cross-half, shfl (DS)
            GETCS(0); ssel_ = (lane & 32) ? s_ : -s_;
#define LRYS(r) { float p_ = __shfl_xor(v##r, 32, 64); v##r = c_ * v##r + ssel_ * p_; }
            ALL32(LRYS)
#undef LRYS
            // qubit 7: mask 16 — shfl (DS)
            GETCS(1); ssel_ = (lane & 16) ? s_ : -s_;
#define LRYS(r) { float p_ = __shfl_xor(v##r, 16, 64); v##r = c_ * v##r + ssel_ * p_; }
            ALL32(LRYS)
#undef LRYS
            // qubit 8: mask 8 — DPP row_shr:8 / row_shl:8 + select
            GETCS(2); ssel_ = (lane & 8) ? s_ : -s_;
#define LRYS(r) { float hi_ = dppf<0x118>(v##r), lo_ = dppf<0x108>(v##r); \
                  float p_ = (lane & 8) ? lo_ : hi_; v##r = c_ * v##r + ssel_ * p_; }
            ALL32(LRYS)
#undef LRYS
            // qubit 9: mask 4 — DPP row_shr:4 / row_shl:4 + select
            GETCS(3); ssel_ = (lane & 4) ? s_ : -s_;
#define LRYS(r) { float hi_ = dppf<0x114>(v##r), lo_ = dppf<0x104>(v##r); \
                  float p_ = (lane & 4) ? lo_ : hi_; v##r = c_ * v##r + ssel_ * p_; }
            ALL32(LRYS)
#undef LRYS
            // qubit 10: mask 2 — DPP quad_perm [2,3,0,1]
            GETCS(4); ssel_ = (lane & 2) ? s_ : -s_;
#define LRYS(r) { float p_ = dppf<0x4E>(v##r); v##r = c_ * v##r + ssel_ * p_; }
            ALL32(LRYS)
#undef LRYS
            // qubit 11: mask 1 — DPP quad_perm [1,0,3,2]
            GETCS(5); ssel_ = (lane & 1) ? s_ : -s_;
#define LRYS(r) { float p_ = dppf<0xB1>(v##r); v##r = c_ * v##r + ssel_ * p_; }
            ALL32(LRYS)
#undef LRYS
#undef GETCS
        }

        // ---- RY on wave-bit qubit 0: 2-phase LDS exchange (8 float2 each)
        {
            float c0_, s0_;
            if constexpr (PRE) { c0_ = csl[0]; s0_ = csl[1]; }
            else { float t_ = 0.5f * qp[12 + l*12]; __sincosf(t_, &s0_, &c0_); }
            const float ssel0_ = w ? s0_ : -s0_;
#define XW(k,a,b) xch2[mybase + (k)] = make_float2(v##a, v##b);
#define XR(k,a,b) { float2 p_ = xch2[pbase + (k)]; \
        v##a = c0_ * v##a + ssel0_ * p_.x; \
        v##b = c0_ * v##b + ssel0_ * p_.y; }
            XA(XW)
            __syncthreads();
            XA(XR)
            __syncthreads();
            XB(XW)
            __syncthreads();
            XB(XR)
            __syncthreads();
#undef XW
#undef XR
        }
    }

    // ---- PauliZ expectation values ----
    float T = 0.f;
#define SQT(r) v##r *= v##r; T += v##r;
    ALL32(SQT)
#undef SQT

    float part[12];
    part[0] = w ? -T : T;                        // qubit 0 sign = wave bit
#define ADDB(a,b) + v##b
    { float S;
      S = 0.f P16(ADDB); part[1] = T - 2.f * S;
      S = 0.f P8(ADDB);  part[2] = T - 2.f * S;
      S = 0.f P4(ADDB);  part[3] = T - 2.f * S;
      S = 0.f P2(ADDB);  part[4] = T - 2.f * S;
      S = 0.f P1(ADDB);  part[5] = T - 2.f * S; }
#undef ADDB
#pragma unroll
    for (int q = 6; q < 12; ++q) {
        const int m = 32 >> (q - 6);
        part[q] = (lane & m) ? -T : T;
    }
#pragma unroll
    for (int q = 0; q < 12; ++q) {
#pragma unroll
        for (int m2 = 32; m2 >= 1; m2 >>= 1) part[q] += __shfl_xor(part[q], m2, 64);
    }
    if (lane == 0) {
#pragma unroll
        for (int q = 0; q < 12; ++q) xchf[w * 12 + q] = part[q];
    }
    __syncthreads();
    if (tid < 12) out[row * 12 + tid] = xchf[tid] + xchf[12 + tid];
}

// ---------------------------------------------------------------------------
extern "C" void kernel_launch(void* const* d_in, const int* in_sizes, int n_in,
                              void* d_out, int out_size, void* d_ws, size_t ws_size,
                              hipStream_t stream) {
    (void)in_sizes; (void)n_in; (void)out_size;
    const float* feats = (const float*)d_in[0];   // (4096, 2048) fp32
    const float* qp    = (const float*)d_in[1];   // (252,) fp32
    float* out = (float*)d_out;                   // (4096, 12) fp32

    if (ws_size >= CS_FLOATS * sizeof(float)) {
        float* cs = (float*)d_ws;
        cs_precompute<<<1, 256, 0, stream>>>(qp, cs);
        qsim<true><<<4096, 128, 0, stream>>>(feats, qp, cs, out);
    } else {
        qsim<false><<<4096, 128, 0, stream>>>(feats, qp, nullptr, out);
    }
}

// Round 9
// 316.938 us; speedup vs baseline: 1.6775x; 1.2317x over previous
//
#include <hip/hip_runtime.h>
#include <math.h>

#define LAYERS 20
#define CS_FLOATS 480   // 20 layers * 12 qubits * {cos,sin}

typedef float f2 __attribute__((ext_vector_type(2)));

// ---------------------------------------------------------------------------
// Pre-kernel: accurate cos/sin of theta/2 for layers 1..20 (weights[1:21]).
// ---------------------------------------------------------------------------
__global__ void cs_precompute(const float* __restrict__ qp, float* __restrict__ cs) {
    int i = threadIdx.x;
    if (i < 240) {
        float t = 0.5f * qp[12 + i];
        cs[2 * i]     = cosf(t);
        cs[2 * i + 1] = sinf(t);
    }
}

// ---------------------------------------------------------------------------
// R8 lessons: (a) q8/q9 row_shr/row_shl DPP pair suspected WRONG (absmax
// 40x jump: bound_ctrl zeros masked by tiny RY angles) -> replace with
// provably-exact primitives: row_ror:8 (rotate by half-row == xor8),
// ds_swizzle BitMode (ISA-specified xor), quad_perm.
// (b) VALU-bound at 70% -> pack state as 16 x float2, RY math in
// v_pk_mul/v_pk_fma (packed fp32, gfx90a+), halving VALU issue count.
//
// Index map: amplitude i = w<<11 | r<<6 | L. wave bit w = qubit 0 (never a
// CNOT target). reg bits r4..r0 = qubits 1..5 (r = 2k|comp, f2 u_k).
// lane bits L5..L0 = qubits 6..11.
// Entangler src map: src = i ^ (i>>1) ^ ((i>>2)&0x155):
//   lane part pl(L) = L^(L>>1)^((L>>2)&5), ^48 iff dest reg bit0;
//   reg part: two static cycle decompositions (w=0 / w=1) below.
// RY q0: cross-wave pair -> 2-phase LDS exchange (f2 slots, pad stride 9).
// ---------------------------------------------------------------------------
// scalar state tokens S0..S31 -> components of u0..u15
#define S0 u0.x
#define S1 u0.y
#define S2 u1.x
#define S3 u1.y
#define S4 u2.x
#define S5 u2.y
#define S6 u3.x
#define S7 u3.y
#define S8 u4.x
#define S9 u4.y
#define S10 u5.x
#define S11 u5.y
#define S12 u6.x
#define S13 u6.y
#define S14 u7.x
#define S15 u7.y
#define S16 u8.x
#define S17 u8.y
#define S18 u9.x
#define S19 u9.y
#define S20 u10.x
#define S21 u10.y
#define S22 u11.x
#define S23 u11.y
#define S24 u12.x
#define S25 u12.y
#define S26 u13.x
#define S27 u13.y
#define S28 u14.x
#define S29 u14.y
#define S30 u15.x
#define S31 u15.y

#define ALL16(F) F(0) F(1) F(2) F(3) F(4) F(5) F(6) F(7) F(8) F(9) F(10) F(11) \
  F(12) F(13) F(14) F(15)
#define ALL32S(F) F(0) F(1) F(2) F(3) F(4) F(5) F(6) F(7) F(8) F(9) F(10) F(11) \
  F(12) F(13) F(14) F(15) F(16) F(17) F(18) F(19) F(20) F(21) F(22) F(23) \
  F(24) F(25) F(26) F(27) F(28) F(29) F(30) F(31)

// f2-pair lists for reg qubits 1..4 (k-masks 8,4,2,1)
#define KQ1(F) F(0,8) F(1,9) F(2,10) F(3,11) F(4,12) F(5,13) F(6,14) F(7,15)
#define KQ2(F) F(0,4) F(1,5) F(2,6) F(3,7) F(8,12) F(9,13) F(10,14) F(11,15)
#define KQ3(F) F(0,2) F(1,3) F(4,6) F(5,7) F(8,10) F(9,11) F(12,14) F(13,15)
#define KQ4(F) F(0,1) F(2,3) F(4,5) F(6,7) F(8,9) F(10,11) F(12,13) F(14,15)

// scalar pair lists for the epilogue sums (reg masks 16,8,4,2,1)
#define P16(F) F(0,16) F(1,17) F(2,18) F(3,19) F(4,20) F(5,21) F(6,22) F(7,23) \
  F(8,24) F(9,25) F(10,26) F(11,27) F(12,28) F(13,29) F(14,30) F(15,31)
#define P8(F) F(0,8) F(1,9) F(2,10) F(3,11) F(4,12) F(5,13) F(6,14) F(7,15) \
  F(16,24) F(17,25) F(18,26) F(19,27) F(20,28) F(21,29) F(22,30) F(23,31)
#define P4(F) F(0,4) F(1,5) F(2,6) F(3,7) F(8,12) F(9,13) F(10,14) F(11,15) \
  F(16,20) F(17,21) F(18,22) F(19,23) F(24,28) F(25,29) F(26,30) F(27,31)
#define P2(F) F(0,2) F(1,3) F(4,6) F(5,7) F(8,10) F(9,11) F(12,14) F(13,15) \
  F(16,18) F(17,19) F(20,22) F(21,23) F(24,26) F(25,27) F(28,30) F(29,31)
#define P1(F) F(0,1) F(2,3) F(4,5) F(6,7) F(8,9) F(10,11) F(12,13) F(14,15) \
  F(16,17) F(18,19) F(20,21) F(22,23) F(24,25) F(26,27) F(28,29) F(30,31)

// q0-exchange phase lists (f2 index)
#define XA16(F) F(0) F(1) F(2) F(3) F(4) F(5) F(6) F(7)
#define XB16(F) F(8) F(9) F(10) F(11) F(12) F(13) F(14) F(15)

// DPP cross-lane fetch (VALU pipe). row_ror:8 = 0x128 (xor8, exact: rotate
// by half of the 16-row == xor). quad_perm 0x4E (xor2), 0xB1 (xor1).
template <int CTRL>
__device__ __forceinline__ float dppf(float x) {
    return __int_as_float(__builtin_amdgcn_mov_dpp(
        __float_as_int(x), CTRL, 0xF, 0xF, true));
}
// ds_swizzle BitMode: offset = (xor<<10)|0x1F. xor16=0x401F, xor4=0x101F.
template <int IMM>
__device__ __forceinline__ float swzf(float x) {
    return __int_as_float(__builtin_amdgcn_ds_swizzle(__float_as_int(x), IMM));
}

// ---------------------------------------------------------------------------
template <bool PRE>
__global__ __launch_bounds__(128)
void qsim(const float* __restrict__ feats,
          const float* __restrict__ qp,
          const float* __restrict__ cs,
          float* __restrict__ out)
{
    __shared__ f2 xch2[2 * 64 * 9];               // 9216 B
    float* xchf = (float*)xch2;

    const int tid  = threadIdx.x;
    const int lane = tid & 63;
    const int w    = tid >> 6;                    // wave bit = qubit 0
    const int row  = blockIdx.x;

    // entangler lane-permutation bpermute byte addresses
    const int sl0     = lane ^ (lane >> 1) ^ ((lane >> 2) & 5);
    const int addr0   = sl0 << 2;
    const int addr1   = (sl0 ^ 48) << 2;
    const int addrX32 = (lane ^ 32) << 2;         // q6 exchange

    const int mybase = w * 576 + lane * 9;        // f2 units, pad stride 9
    const int pbase  = (1 - w) * 576 + lane * 9;

#define DCLU(k) f2 u##k;
    ALL16(DCLU)
#undef DCLU

    // ---- load + tanh + amplitude embedding ----
    const float* fr = feats + (size_t)row * 2048;
    if (w == 0) {                                 // amplitudes 0..2047 = features
        float fsum = 0.f;
#define LD(r) { float x_ = tanhf(fr[((r) << 6) + lane]) * 1.5707963267948966f; \
                S##r = x_; fsum += x_ * x_; }
        ALL32S(LD)
#undef LD
#pragma unroll
        for (int m = 32; m >= 1; m >>= 1) fsum += __shfl_xor(fsum, m, 64);
        if (lane == 0) xchf[0] = fsum;
    }
    __syncthreads();
    const float inv = rsqrtf(xchf[0] + 512.0f);   // 2048 pads of 0.5^2
    __syncthreads();                              // protect xchf[0] before reuse
    if (w == 0) {
#define SC(k) u##k *= inv;
        ALL16(SC)
#undef SC
    } else {                                      // amplitudes 2048..4095 = 0.5
        const float padv = 0.5f * inv;
        const f2 pv2 = {padv, padv};
#define PD(k) u##k = pv2;
        ALL16(PD)
#undef PD
    }

    // ---- 20 circuit layers ----
#pragma unroll 1
    for (int l = 0; l < LAYERS; ++l) {
        const float* csl = cs + l * 24;

        // ---- entangling layer (32 ds_bpermute on scalar components) ----
#define BPV(a, x) __int_as_float(__builtin_amdgcn_ds_bpermute( \
                      (((a) & 1) ? addr1 : addr0), __float_as_int(x)))
#define FIX(a) S##a = BPV(a, S##a);
#define C2(a,b) { float t_ = S##a; S##a = BPV(a, S##b); S##b = BPV(b, t_); }
#define C4(a,b,c,d) { float t_ = S##a; S##a = BPV(a, S##b); \
        S##b = BPV(b, S##c); S##c = BPV(c, S##d); S##d = BPV(d, t_); }
#define C8(a,b,c,d,e,f,g,h) { float t_ = S##a; S##a = BPV(a, S##b); \
        S##b = BPV(b, S##c); S##c = BPV(c, S##d); S##d = BPV(d, S##e); \
        S##e = BPV(e, S##f); S##f = BPV(f, S##g); S##g = BPV(g, S##h); \
        S##h = BPV(h, t_); }
        if (w == 0) {
            FIX(0) FIX(1)
            C2(2, 3)
            C4(4, 7, 5, 6)
            C4(8, 12, 11, 14)
            C4(9, 13, 10, 15)
            C8(16, 28, 23, 25, 17, 29, 22, 24)
            C8(18, 31, 21, 26, 19, 30, 20, 27)
        } else {
            C8(0, 16, 12, 27, 2, 19, 14, 24)
            C8(1, 17, 13, 26, 3, 18, 15, 25)
            C8(4, 23, 9, 29, 6, 20, 11, 30)
            C8(5, 22, 8, 28, 7, 21, 10, 31)
        }
#undef BPV
#undef FIX
#undef C2
#undef C4
#undef C8

        // ---- RY on reg-bit qubits 1..4 (f2-pair rotations, packed fp32)
#define RYPK(a,b) { f2 A_ = u##a, B_ = u##b; \
        u##a = c_ * A_ - s_ * B_; u##b = s_ * A_ + c_ * B_; }
#define RYREGK(J, LIST) { float c_, s_; \
        if constexpr (PRE) { c_ = csl[2*(J)]; s_ = csl[2*(J)+1]; } \
        else { float t_ = 0.5f * qp[12 + l*12 + (J)]; __sincosf(t_, &s_, &c_); } \
        LIST(RYPK) }
        RYREGK(1, KQ1)
        RYREGK(2, KQ2)
        RYREGK(3, KQ3)
        RYREGK(4, KQ4)
#undef RYREGK
#undef RYPK

        // ---- RY on reg-bit qubit 5 (within-f2 rotation)
        {
            float c_, s_;
            if constexpr (PRE) { c_ = csl[10]; s_ = csl[11]; }
            else { float t_ = 0.5f * qp[12 + l*12 + 5]; __sincosf(t_, &s_, &c_); }
            const f2 ss5_ = {-s_, s_};
#define Q5(k) { f2 sw_ = u##k.yx; u##k = c_ * u##k + ss5_ * sw_; }
            ALL16(Q5)
#undef Q5
        }

        // ---- RY on lane-bit qubits 6..11 (exact exchanges only) ----
        {
            float c_, s_, ssel_;
#define GETCS(jj) \
            if constexpr (PRE) { c_ = csl[12 + 2*(jj)]; s_ = csl[13 + 2*(jj)]; } \
            else { float t_ = 0.5f * qp[12 + l*12 + 6 + (jj)]; __sincosf(t_, &s_, &c_); }
#define LQ(k, EX) { f2 p_; p_.x = EX(u##k.x); p_.y = EX(u##k.y); \
                    u##k = c_ * u##k + ssel_ * p_; }

            // qubit 6: xor32 — ds_bpermute, precomputed address
            GETCS(0); ssel_ = (lane & 32) ? s_ : -s_;
#define EX6(x) __int_as_float(__builtin_amdgcn_ds_bpermute(addrX32, __float_as_int(x)))
#define LQ6(k) LQ(k, EX6)
            ALL16(LQ6)
#undef LQ6
#undef EX6
            // qubit 7: xor16 — ds_swizzle 0x401F
            GETCS(1); ssel_ = (lane & 16) ? s_ : -s_;
#define LQ7(k) LQ(k, swzf<0x401F>)
            ALL16(LQ7)
#undef LQ7
            // qubit 8: xor8 — DPP row_ror:8 (exact rotation == xor)
            GETCS(2); ssel_ = (lane & 8) ? s_ : -s_;
#define LQ8(k) LQ(k, dppf<0x128>)
            ALL16(LQ8)
#undef LQ8
            // qubit 9: xor4 — ds_swizzle 0x101F
            GETCS(3); ssel_ = (lane & 4) ? s_ : -s_;
#define LQ9(k) LQ(k, swzf<0x101F>)
            ALL16(LQ9)
#undef LQ9
            // qubit 10: xor2 — DPP quad_perm [2,3,0,1]
            GETCS(4); ssel_ = (lane & 2) ? s_ : -s_;
#define LQ10(k) LQ(k, dppf<0x4E>)
            ALL16(LQ10)
#undef LQ10
            // qubit 11: xor1 — DPP quad_perm [1,0,3,2]
            GETCS(5); ssel_ = (lane & 1) ? s_ : -s_;
#define LQ11(k) LQ(k, dppf<0xB1>)
            ALL16(LQ11)
#undef LQ11
#undef LQ
#undef GETCS
        }

        // ---- RY on wave-bit qubit 0: 2-phase LDS exchange (f2 slots) ----
        {
            float c0_, s0_;
            if constexpr (PRE) { c0_ = csl[0]; s0_ = csl[1]; }
            else { float t_ = 0.5f * qp[12 + l*12]; __sincosf(t_, &s0_, &c0_); }
            const float ssel0_ = w ? s0_ : -s0_;
#define XWA(k) xch2[mybase + (k)] = u##k;
#define XRA(k) { f2 p_ = xch2[pbase + (k)]; u##k = c0_ * u##k + ssel0_ * p_; }
#define XWB(k) xch2[mybase + ((k) - 8)] = u##k;
#define XRB(k) { f2 p_ = xch2[pbase + ((k) - 8)]; u##k = c0_ * u##k + ssel0_ * p_; }
            XA16(XWA)
            __syncthreads();
            XA16(XRA)
            __syncthreads();
            XB16(XWB)
            __syncthreads();
            XB16(XRB)
            __syncthreads();
#undef XWA
#undef XRA
#undef XWB
#undef XRB
        }
    }

    // ---- PauliZ expectation values ----
    float T = 0.f;
#define SQT(k) u##k *= u##k; T += u##k.x + u##k.y;
    ALL16(SQT)
#undef SQT

    float part[12];
    part[0] = w ? -T : T;                        // qubit 0 sign = wave bit
#define ADDB(a,b) + S##b
    { float S;
      S = 0.f P16(ADDB); part[1] = T - 2.f * S;
      S = 0.f P8(ADDB);  part[2] = T - 2.f * S;
      S = 0.f P4(ADDB);  part[3] = T - 2.f * S;
      S = 0.f P2(ADDB);  part[4] = T - 2.f * S;
      S = 0.f P1(ADDB);  part[5] = T - 2.f * S; }
#undef ADDB
#pragma unroll
    for (int q = 6; q < 12; ++q) {
        const int m = 32 >> (q - 6);
        part[q] = (lane & m) ? -T : T;
    }
#pragma unroll
    for (int q = 0; q < 12; ++q) {
#pragma unroll
        for (int m2 = 32; m2 >= 1; m2 >>= 1) part[q] += __shfl_xor(part[q], m2, 64);
    }
    if (lane == 0) {
#pragma unroll
        for (int q = 0; q < 12; ++q) xchf[w * 12 + q] = part[q];
    }
    __syncthreads();
    if (tid < 12) out[row * 12 + tid] = xchf[tid] + xchf[12 + tid];
}

// ---------------------------------------------------------------------------
extern "C" void kernel_launch(void* const* d_in, const int* in_sizes, int n_in,
                              void* d_out, int out_size, void* d_ws, size_t ws_size,
                              hipStream_t stream) {
    (void)in_sizes; (void)n_in; (void)out_size;
    const float* feats = (const float*)d_in[0];   // (4096, 2048) fp32
    const float* qp    = (const float*)d_in[1];   // (252,) fp32
    float* out = (float*)d_out;                   // (4096, 12) fp32

    if (ws_size >= CS_FLOATS * sizeof(float)) {
        float* cs = (float*)d_ws;
        cs_precompute<<<1, 256, 0, stream>>>(qp, cs);
        qsim<true><<<4096, 128, 0, stream>>>(feats, qp, cs, out);
    } else {
        qsim<false><<<4096, 128, 0, stream>>>(feats, qp, nullptr, out);
    }
}